// Round 3
// baseline (198.253 us; speedup 1.0000x reference)
//
#include <hip/hip_runtime.h>
#include <stdint.h>

typedef unsigned short u16;
typedef __attribute__((ext_vector_type(8))) short short8;   // 8 x bf16 (4 VGPRs)
typedef __attribute__((ext_vector_type(4))) float f32x4;    // 4 x fp32 acc

__device__ __forceinline__ u16 f2bf(float f) {
    union { float f; uint32_t u; } v; v.f = f;
    return (u16)((v.u + (0x7FFFu + ((v.u >> 16) & 1u))) >> 16);   // RNE
}

// ---------------- P1: W2[o][j] = sum_i U[o][i] * S[i][j]  (256x64, bf16 out) ----
__global__ void k_us(const float* __restrict__ U, const float* __restrict__ S,
                     u16* __restrict__ W2) {
    int t = blockIdx.x * 256 + threadIdx.x;        // 16384 threads
    int o = t >> 6, j = t & 63;
    float acc = 0.f;
#pragma unroll 8
    for (int i = 0; i < 64; ++i) acc += U[o * 64 + i] * S[i * 64 + j];
    W2[t] = f2bf(acc);
}

// ---------------- P2: Vt[r][tap*256 + c] = V[c*9 + tap][r]  (bf16) --------------
__global__ void k_vperm(const float* __restrict__ V, u16* __restrict__ Vt) {
    int t = blockIdx.x * 256 + threadIdx.x;        // 147456 threads
    int c = t & 255;
    int tap = (t >> 8) % 9;
    int r = t / 2304;
    Vt[t] = f2bf(V[(c * 9 + tap) * 64 + r]);
}

// ---------------- P3: coalesced LDS-tiled transpose+pad  -----------------------
// xb[b][hp][wp][c] (bf16, [16][58][58][256]) from x[b][c][h][w] fp32.
__global__ __launch_bounds__(256) void k_tr(const float* __restrict__ x,
                                            u16* __restrict__ xb) {
    __shared__ uint32_t lds[64 * 57];               // 14592 B
    int bi = blockIdx.x;                            // 16*58*2 = 1856
    int cg = bi & 1;
    int hp = (bi >> 1) % 58;
    int b  = bi / 116;
    int c0 = cg * 128;
    int tid = threadIdx.x;

    uint32_t* xbrow32 = (uint32_t*)(xb + ((size_t)(b * 58 + hp) * 58) * 256 + c0);

    if (hp == 0 || hp == 57) {                      // border row: all zeros
        for (int i = tid; i < 58 * 64; i += 256)
            xbrow32[(i >> 6) * 128 + (i & 63)] = 0u;
        return;
    }

    int h = hp - 1;
    int w = tid & 63;                               // 56 valid
    int cpq = tid >> 6;                             // 0..3
    const float* xbase = x + ((size_t)(b * 256 + c0) * 3136) + h * 56 + w;
    if (w < 56) {
#pragma unroll
        for (int k = 0; k < 16; ++k) {
            int cp = cpq * 16 + k;                  // channel pair 0..63
            float a0 = xbase[(size_t)(2 * cp) * 3136];
            float a1 = xbase[(size_t)(2 * cp + 1) * 3136];
            lds[cp * 57 + w] = (uint32_t)f2bf(a0) | ((uint32_t)f2bf(a1) << 16);
        }
    }
    __syncthreads();

    int cpair = tid & 63;
    int wpq = tid >> 6;
#pragma unroll
    for (int wp = wpq; wp < 58; wp += 4) {
        uint32_t v = (wp == 0 || wp == 57) ? 0u : lds[cpair * 57 + (wp - 1)];
        xbrow32[wp * 128 + cpair] = v;
    }
}

// ---------------- Stage A v3: barrier-free K-split register GEMM ---------------
// y1[l][r] = sum_{tap,c} Vt[r][tap*256+c] * xpad[l-tap-shifted][c]
// grid = 784 tiles of 64 l (50176/64, exact; 3136 = 49*64 so no b-crossing).
// 4 waves/block: wave kv owns channel quarter [kv*64, kv*64+64), ALL 9 taps.
// Wave tile 64r x 64l: 4 A-frags x 4 B-frags -> 16 MFMA per 8 global loads.
// NO LDS / NO barriers in the K-loop; im2col = constant per-tap byte offsets.
// Final 4-way partial reduction via LDS ([frag][lane] layout, conflict-free).
__global__ __launch_bounds__(256, 3) void k_convA(const u16* __restrict__ xb,
                                                  const u16* __restrict__ Vt,
                                                  u16* __restrict__ y1) {
    __shared__ f32x4 red[2][16 * 64];               // 2 x 16 KB
    int tile = blockIdx.x;                          // 784
    int tid = threadIdx.x;
    int kv = tid >> 6;                              // K-quarter 0..3
    int ln = tid & 63;
    int lane15 = ln & 15, quad = ln >> 4;

    // per-nt B base pointers (lane15 -> l, quad -> 16B k-slice, kv folded in)
    const u16* bbase[4];
#pragma unroll
    for (int nt = 0; nt < 4; ++nt) {
        int l = tile * 64 + nt * 16 + lane15;
        int b = l / 3136;
        int hw = l - b * 3136;
        int h = hw / 56, w = hw - h * 56;
        bbase[nt] = xb + (((size_t)(b * 58 + h) * 58 + w) << 8) + kv * 64 + quad * 8;
    }
    const u16* abase = Vt + (size_t)lane15 * 2304 + kv * 64 + quad * 8;

    f32x4 acc[4][4];
#pragma unroll
    for (int mt = 0; mt < 4; ++mt)
#pragma unroll
        for (int nt = 0; nt < 4; ++nt) acc[mt][nt] = (f32x4){0.f, 0.f, 0.f, 0.f};

#pragma unroll
    for (int cs = 0; cs < 64; cs += 32) {
#pragma unroll
        for (int tap = 0; tap < 9; ++tap) {
            const int di = tap / 3, dj = tap % 3;
            const int boff = (di * 58 + dj) * 256 + cs;   // compile-time const
            short8 a[4], bv[4];
#pragma unroll
            for (int mt = 0; mt < 4; ++mt)
                a[mt] = *(const short8*)(abase + (size_t)mt * 16 * 2304
                                         + tap * 256 + cs);
#pragma unroll
            for (int nt = 0; nt < 4; ++nt)
                bv[nt] = *(const short8*)(bbase[nt] + boff);
#pragma unroll
            for (int mt = 0; mt < 4; ++mt)
#pragma unroll
                for (int nt = 0; nt < 4; ++nt)
                    acc[mt][nt] = __builtin_amdgcn_mfma_f32_16x16x32_bf16(
                        a[mt], bv[nt], acc[mt][nt], 0, 0, 0);
        }
    }

    // 4-way partial reduction: kv1->red0, kv3->red1; kv0+=red0, kv2+=red1->red1;
    // kv0+=red1, stores.
    if (kv == 1 || kv == 3) {
        f32x4* dst = red[kv >> 1];
#pragma unroll
        for (int f = 0; f < 16; ++f) dst[f * 64 + ln] = acc[f >> 2][f & 3];
    }
    __syncthreads();
    if (kv == 0) {
#pragma unroll
        for (int f = 0; f < 16; ++f) acc[f >> 2][f & 3] += red[0][f * 64 + ln];
    } else if (kv == 2) {
#pragma unroll
        for (int f = 0; f < 16; ++f) {
            f32x4 v = acc[f >> 2][f & 3] + red[1][f * 64 + ln];
            red[1][f * 64 + ln] = v;
        }
    }
    __syncthreads();
    if (kv == 0) {
#pragma unroll
        for (int mt = 0; mt < 4; ++mt)
#pragma unroll
            for (int nt = 0; nt < 4; ++nt) {
                f32x4 v = acc[mt][nt] + red[1][(mt * 4 + nt) * 64 + ln];
                int l = tile * 64 + nt * 16 + lane15;
                uint2 pv;
                pv.x = (uint32_t)f2bf(v[0]) | ((uint32_t)f2bf(v[1]) << 16);
                pv.y = (uint32_t)f2bf(v[2]) | ((uint32_t)f2bf(v[3]) << 16);
                *(uint2*)(y1 + ((size_t)l << 6) + mt * 16 + quad * 4) = pv;
            }
    }
}

// ---------------- Stage B: out[b][o][l] = W2[o][:] . y1[b][l][:] + bias[o] -----
__global__ __launch_bounds__(256) void k_gemmB(const u16* __restrict__ y1,
                                               const u16* __restrict__ W2,
                                               const float* __restrict__ bias,
                                               float* __restrict__ out) {
    __shared__ u16 lds_y[64 * 72];                  // 9216 B
    int bi = blockIdx.x;                            // 784 = 16*49
    int b = bi % 16, lt = bi / 16;
    int l0 = lt * 64;
    int tid = threadIdx.x;
    int wv = tid >> 6, ln = tid & 63;
    int lane15 = ln & 15, quad = ln >> 4;

    for (int idx = tid; idx < 512; idx += 256) {
        int q = idx & 7, n = idx >> 3;
        uint4 v = *(const uint4*)(y1 + (((size_t)(b * 3136 + l0 + n)) << 6) + q * 8);
        *(uint4*)&lds_y[n * 72 + q * 8] = v;
    }
    __syncthreads();

    f32x4 acc[4][4];
#pragma unroll
    for (int mt = 0; mt < 4; ++mt)
#pragma unroll
        for (int nt = 0; nt < 4; ++nt) acc[mt][nt] = (f32x4){0.f, 0.f, 0.f, 0.f};

    int o0 = wv * 64;
#pragma unroll
    for (int ks = 0; ks < 64; ks += 32) {
        short8 a[4];
#pragma unroll
        for (int mt = 0; mt < 4; ++mt)
            a[mt] = *(const short8*)(W2 + (size_t)(o0 + mt * 16 + lane15) * 64
                                     + ks + quad * 8);
#pragma unroll
        for (int nt = 0; nt < 4; ++nt) {
            short8 bv = *(const short8*)&lds_y[(nt * 16 + lane15) * 72 + ks + quad * 8];
#pragma unroll
            for (int mt = 0; mt < 4; ++mt)
                acc[mt][nt] = __builtin_amdgcn_mfma_f32_16x16x32_bf16(a[mt], bv, acc[mt][nt], 0, 0, 0);
        }
    }

#pragma unroll
    for (int mt = 0; mt < 4; ++mt) {
        int ob = o0 + mt * 16 + quad * 4;
#pragma unroll
        for (int reg = 0; reg < 4; ++reg) {
            int o = ob + reg;
            float bvl = bias[o];
            float* orow = out + ((size_t)(b * 256 + o)) * 3136 + l0 + lane15;
#pragma unroll
            for (int nt = 0; nt < 4; ++nt)
                orow[nt * 16] = acc[mt][nt][reg] + bvl;
        }
    }
}

extern "C" void kernel_launch(void* const* d_in, const int* in_sizes, int n_in,
                              void* d_out, int out_size, void* d_ws, size_t ws_size,
                              hipStream_t stream) {
    const float* x    = (const float*)d_in[0];   // [16,256,56,56]
    const float* U    = (const float*)d_in[1];   // [256,64]
    const float* S    = (const float*)d_in[2];   // [64,64]
    const float* V    = (const float*)d_in[3];   // [2304,64]
    const float* bias = (const float*)d_in[4];   // [256]
    float* out = (float*)d_out;                  // [16,256,56,56] fp32

    char* ws = (char*)d_ws;
    u16* xb = (u16*)ws;                                   // 27,557,888 B
    u16* Vt = (u16*)(ws + 27557888);                      //    294,912 B
    u16* W2 = (u16*)(ws + 27557888 + 294912);             //     32,768 B
    u16* y1 = (u16*)(ws + 27557888 + 294912 + 32768);     //  6,422,528 B

    k_us   <<<64,   256, 0, stream>>>(U, S, W2);
    k_vperm<<<576,  256, 0, stream>>>(V, Vt);
    k_tr   <<<1856, 256, 0, stream>>>(x, xb);
    k_convA<<<784,  256, 0, stream>>>(xb, Vt, y1);
    k_gemmB<<<784,  256, 0, stream>>>(y1, W2, bias, out);
}

// Round 4
// 152.390 us; speedup vs baseline: 1.3010x; 1.3010x over previous
//
#include <hip/hip_runtime.h>
#include <stdint.h>

typedef unsigned short u16;
typedef __attribute__((ext_vector_type(8))) short short8;   // 8 x bf16 (4 VGPRs)
typedef __attribute__((ext_vector_type(4))) float f32x4;    // 4 x fp32 acc

typedef __attribute__((address_space(3))) uint8_t* lds_ptr_t;
typedef const __attribute__((address_space(1))) uint8_t* gbl_ptr_t;

__device__ __forceinline__ u16 f2bf(float f) {
    union { float f; uint32_t u; } v; v.f = f;
    return (u16)((v.u + (0x7FFFu + ((v.u >> 16) & 1u))) >> 16);   // RNE
}

// ---------------- P1: W2[o][j] = sum_i U[o][i] * S[i][j]  (256x64, bf16 out) ----
__global__ void k_us(const float* __restrict__ U, const float* __restrict__ S,
                     u16* __restrict__ W2) {
    int t = blockIdx.x * 256 + threadIdx.x;        // 16384 threads
    int o = t >> 6, j = t & 63;
    float acc = 0.f;
#pragma unroll 8
    for (int i = 0; i < 64; ++i) acc += U[o * 64 + i] * S[i * 64 + j];
    W2[t] = f2bf(acc);
}

// ---------------- P2: Vp = V packed in exact MFMA A-fragment order -------------
// frag(kv,tap,cc,mt): 1024 B, lane ln holds 16 B at ln*16 = A[m=mt*16+(ln&15)]
// [k = quad*8+e] with c = kv*64+cc*32+quad*8+e. One coalesced 1KB load/frag.
__global__ void k_vpack(const float* __restrict__ V, u16* __restrict__ Vp) {
    int t = blockIdx.x * 256 + threadIdx.x;        // 18432 threads (72 blocks)
    int ln = t & 63, mt = (t >> 6) & 3, cc = (t >> 8) & 1;
    int tap = (t >> 9) % 9, kv = t / 4608;
    int r = mt * 16 + (ln & 15);
    int cb = kv * 64 + cc * 32 + (ln >> 4) * 8;
    u16 tmp[8];
#pragma unroll
    for (int e = 0; e < 8; ++e)
        tmp[e] = f2bf(V[(size_t)((cb + e) * 9 + tap) * 64 + r]);
    *(uint4*)(Vp + (size_t)t * 8) = *(uint4*)tmp;
}

// ---------------- P3: coalesced LDS-tiled transpose+pad  -----------------------
// xb[b][hp][wp][c] (bf16, [16][58][58][256]) from x[b][c][h][w] fp32.
__global__ __launch_bounds__(256) void k_tr(const float* __restrict__ x,
                                            u16* __restrict__ xb) {
    __shared__ uint32_t lds[64 * 57];               // 14592 B
    int bi = blockIdx.x;                            // 16*58*2 = 1856
    int cg = bi & 1;
    int hp = (bi >> 1) % 58;
    int b  = bi / 116;
    int c0 = cg * 128;
    int tid = threadIdx.x;

    uint32_t* xbrow32 = (uint32_t*)(xb + ((size_t)(b * 58 + hp) * 58) * 256 + c0);

    if (hp == 0 || hp == 57) {                      // border row: all zeros
        for (int i = tid; i < 58 * 64; i += 256)
            xbrow32[(i >> 6) * 128 + (i & 63)] = 0u;
        return;
    }

    int h = hp - 1;
    int w = tid & 63;                               // 56 valid
    int cpq = tid >> 6;                             // 0..3
    const float* xbase = x + ((size_t)(b * 256 + c0) * 3136) + h * 56 + w;
    if (w < 56) {
#pragma unroll
        for (int k = 0; k < 16; ++k) {
            int cp = cpq * 16 + k;                  // channel pair 0..63
            float a0 = xbase[(size_t)(2 * cp) * 3136];
            float a1 = xbase[(size_t)(2 * cp + 1) * 3136];
            lds[cp * 57 + w] = (uint32_t)f2bf(a0) | ((uint32_t)f2bf(a1) << 16);
        }
    }
    __syncthreads();

    int cpair = tid & 63;
    int wpq = tid >> 6;
#pragma unroll
    for (int wp = wpq; wp < 58; wp += 4) {
        uint32_t v = (wp == 0 || wp == 57) ? 0u : lds[cpair * 57 + (wp - 1)];
        xbrow32[wp * 128 + cpair] = v;
    }
}

// ---------------- Stage A v4: one-barrier LDS conv GEMM ------------------------
// Block = 8x8 output tile (784 = 16b x 7ht x 7wt). Stage the full 10x10x256c
// halo window (51.2 KB) ONCE via global_load_lds w/ XOR-swizzled slots, then an
// 18-step K-loop per wave (K-split-4 over channels), zero barriers inside.
// Every wave holds all 64 r (4 mt) -> each bv feeds 4 MFMAs. A-frags are 1KB
// coalesced global loads from Vp (L2-hot). Conflict-free ds_read_b128 by swizzle.
__global__ __launch_bounds__(256, 2) void k_convA(const u16* __restrict__ xb,
                                                  const u16* __restrict__ Vp,
                                                  u16* __restrict__ y1) {
    __shared__ u16 lds[100 * 256];                  // 51200 B: [cell][512B swizzled]
    int bi = blockIdx.x;                            // 784
    int wt = bi % 7, ht = (bi / 7) % 7, b = bi / 49;
    int h0 = ht * 8, w0 = wt * 8;
    int tid = threadIdx.x;
    int kv = tid >> 6, ln = tid & 63;
    int lane15 = ln & 15, quad = ln >> 4;

    // ---- stage: 50 instrs x 1KB; lane j of cell fetches slice (j ^ (cell&7)) ----
    {
        int cs2 = ln >> 5;                          // which of the 2 cells/instr
        int j   = ln & 31;
        int cell = cs2, rr = 0, wp = cs2;
        const u16* gw = xb + (((size_t)(b * 58 + h0)) * 58 + w0) * 256;
        char* lb = (char*)lds;
        for (int i = 0; i < 50; ++i) {
            const u16* g = gw + (rr * 58 + wp) * 256 + ((j ^ (cell & 7)) << 3);
            __builtin_amdgcn_global_load_lds((gbl_ptr_t)g,
                                             (lds_ptr_t)(lb + i * 1024), 16, 0, 0);
            cell += 2; wp += 2;
            int wrap = (wp >= 10) ? 1 : 0;
            wp -= wrap * 10; rr += wrap;
        }
    }
    __syncthreads();

    // ---- K-loop: 9 taps x 2 cc (32c each) = 18 MFMA k-steps, no barriers ----
    int dh = lane15 >> 3, dw = lane15 & 7;
    int cell00 = dh * 10 + dw;
    int jbase = (kv << 3) + quad;                   // j' = kv*8 + cc*4 + quad
    const char* lb = (const char*)lds;

    f32x4 acc[4][4];
#pragma unroll
    for (int mt = 0; mt < 4; ++mt)
#pragma unroll
        for (int nt = 0; nt < 4; ++nt) acc[mt][nt] = (f32x4){0.f, 0.f, 0.f, 0.f};

#pragma unroll
    for (int tap = 0; tap < 9; ++tap) {
        const int di = tap / 3, dj = tap % 3;
#pragma unroll
        for (int cc = 0; cc < 2; ++cc) {
            const u16* ab = Vp + ((size_t)(((kv * 9 + tap) * 2 + cc) * 4) * 512)
                          + ln * 8;
            short8 a[4];
#pragma unroll
            for (int mt = 0; mt < 4; ++mt)
                a[mt] = *(const short8*)(ab + mt * 512);
            int jj = jbase + (cc << 2);
            short8 bv[4];
#pragma unroll
            for (int nt = 0; nt < 4; ++nt) {
                int cell = cell00 + nt * 20 + di * 10 + dj;
                int off = cell * 512 + ((jj ^ (cell & 7)) << 4);
                bv[nt] = *(const short8*)(lb + off);
            }
#pragma unroll
            for (int mt = 0; mt < 4; ++mt)
#pragma unroll
                for (int nt = 0; nt < 4; ++nt)
                    acc[mt][nt] = __builtin_amdgcn_mfma_f32_16x16x32_bf16(
                        a[mt], bv[nt], acc[mt][nt], 0, 0, 0);
        }
    }

    // ---- 4-way K-split reduction (reuse x-LDS; 32KB <= 51.2KB) ----
    __syncthreads();                                // all ds_reads of x done
    f32x4* red = (f32x4*)lds;
    if (kv & 1) {                                   // kv 1 -> red[0..15], 3 -> [16..31]
        f32x4* dst = red + ((kv >> 1) * 16) * 64;
#pragma unroll
        for (int f = 0; f < 16; ++f) dst[f * 64 + ln] = acc[f >> 2][f & 3];
    }
    __syncthreads();
    if (kv == 0) {
#pragma unroll
        for (int f = 0; f < 16; ++f) acc[f >> 2][f & 3] += red[f * 64 + ln];
    } else if (kv == 2) {
#pragma unroll
        for (int f = 0; f < 16; ++f) red[(16 + f) * 64 + ln] += acc[f >> 2][f & 3];
    }
    __syncthreads();
    if (kv == 0) {
#pragma unroll
        for (int mt = 0; mt < 4; ++mt)
#pragma unroll
            for (int nt = 0; nt < 4; ++nt) {
                f32x4 v = acc[mt][nt] + red[(16 + mt * 4 + nt) * 64 + ln];
                int oh = nt * 2 + dh, ow = dw;
                int l = b * 3136 + (h0 + oh) * 56 + (w0 + ow);
                uint2 pv;
                pv.x = (uint32_t)f2bf(v[0]) | ((uint32_t)f2bf(v[1]) << 16);
                pv.y = (uint32_t)f2bf(v[2]) | ((uint32_t)f2bf(v[3]) << 16);
                *(uint2*)(y1 + ((size_t)l << 6) + mt * 16 + quad * 4) = pv;
            }
    }
}

// ---------------- Stage B: out[b][o][l] = W2[o][:] . y1[b][l][:] + bias[o] -----
__global__ __launch_bounds__(256) void k_gemmB(const u16* __restrict__ y1,
                                               const u16* __restrict__ W2,
                                               const float* __restrict__ bias,
                                               float* __restrict__ out) {
    __shared__ u16 lds_y[64 * 72];                  // 9216 B
    int bi = blockIdx.x;                            // 784 = 16*49
    int b = bi % 16, lt = bi / 16;
    int l0 = lt * 64;
    int tid = threadIdx.x;
    int wv = tid >> 6, ln = tid & 63;
    int lane15 = ln & 15, quad = ln >> 4;

    for (int idx = tid; idx < 512; idx += 256) {
        int q = idx & 7, n = idx >> 3;
        uint4 v = *(const uint4*)(y1 + (((size_t)(b * 3136 + l0 + n)) << 6) + q * 8);
        *(uint4*)&lds_y[n * 72 + q * 8] = v;
    }
    __syncthreads();

    f32x4 acc[4][4];
#pragma unroll
    for (int mt = 0; mt < 4; ++mt)
#pragma unroll
        for (int nt = 0; nt < 4; ++nt) acc[mt][nt] = (f32x4){0.f, 0.f, 0.f, 0.f};

    int o0 = wv * 64;
#pragma unroll
    for (int ks = 0; ks < 64; ks += 32) {
        short8 a[4];
#pragma unroll
        for (int mt = 0; mt < 4; ++mt)
            a[mt] = *(const short8*)(W2 + (size_t)(o0 + mt * 16 + lane15) * 64
                                     + ks + quad * 8);
#pragma unroll
        for (int nt = 0; nt < 4; ++nt) {
            short8 bv = *(const short8*)&lds_y[(nt * 16 + lane15) * 72 + ks + quad * 8];
#pragma unroll
            for (int mt = 0; mt < 4; ++mt)
                acc[mt][nt] = __builtin_amdgcn_mfma_f32_16x16x32_bf16(a[mt], bv, acc[mt][nt], 0, 0, 0);
        }
    }

#pragma unroll
    for (int mt = 0; mt < 4; ++mt) {
        int ob = o0 + mt * 16 + quad * 4;
#pragma unroll
        for (int reg = 0; reg < 4; ++reg) {
            int o = ob + reg;
            float bvl = bias[o];
            float* orow = out + ((size_t)(b * 256 + o)) * 3136 + l0 + lane15;
#pragma unroll
            for (int nt = 0; nt < 4; ++nt)
                orow[nt * 16] = acc[mt][nt][reg] + bvl;
        }
    }
}

extern "C" void kernel_launch(void* const* d_in, const int* in_sizes, int n_in,
                              void* d_out, int out_size, void* d_ws, size_t ws_size,
                              hipStream_t stream) {
    const float* x    = (const float*)d_in[0];   // [16,256,56,56]
    const float* U    = (const float*)d_in[1];   // [256,64]
    const float* S    = (const float*)d_in[2];   // [64,64]
    const float* V    = (const float*)d_in[3];   // [2304,64]
    const float* bias = (const float*)d_in[4];   // [256]
    float* out = (float*)d_out;                  // [16,256,56,56] fp32

    char* ws = (char*)d_ws;
    u16* xb = (u16*)ws;                                   // 27,557,888 B
    u16* Vp = (u16*)(ws + 27557888);                      //    294,912 B
    u16* W2 = (u16*)(ws + 27557888 + 294912);             //     32,768 B
    u16* y1 = (u16*)(ws + 27557888 + 294912 + 32768);     //  6,422,528 B

    k_us   <<<64,   256, 0, stream>>>(U, S, W2);
    k_vpack<<<72,   256, 0, stream>>>(V, Vp);
    k_tr   <<<1856, 256, 0, stream>>>(x, xb);
    k_convA<<<784,  256, 0, stream>>>(xb, Vp, y1);
    k_gemmB<<<784,  256, 0, stream>>>(y1, W2, bias, out);
}